// Round 1
// baseline (15.758 us; speedup 1.0000x reference)
//
#include <hip/hip_runtime.h>

// LegendreActivation: out[b,o] = sum_w coeffs[o,w] * S[b,w]
// where S[b,w] = sum_i P_w(tanh(x[b,i]*scale)),  S[b,0] == 1024 exactly.
// B=4096, I=1024, O=1024, W=9 (degrees 0..8).

constexpr int I_DIM = 1024;
constexpr int O_DIM = 1024;
constexpr int G     = 8;    // rows per block
constexpr int NT    = 256;  // threads per block

__global__ __launch_bounds__(NT, 4) void legendre_fused(
    const float* __restrict__ x,
    const float* __restrict__ coeffs,
    const float* __restrict__ scale_p,
    float* __restrict__ out)
{
    __shared__ float S_lds[G][8];   // sums for w = 1..8 (w=0 is constant 1024)

    const int t  = threadIdx.x;
    const int b0 = blockIdx.x * G;
    const int g  = t >> 5;          // row group 0..7 (32 lanes each)
    const int lg = t & 31;          // lane within group

    float sc = scale_p[0];
    sc = fminf(fmaxf(sc, 0.1f), 2.0f);
    // combined constant: xs = tanh(x*sc); tanh(z) = 1 - 2/(exp2(z*2*log2e)+1)
    const float K = sc * 2.8853900817779268f;  // sc * 2*log2(e)

    // Bonnet recursion coefficients for n = 2..8: a=(2n-1)/n, b=(n-1)/n
    const float An[7] = {1.5f, 5.f/3.f, 1.75f, 1.8f, 11.f/6.f, 13.f/7.f, 1.875f};
    const float Bn[7] = {0.5f, 2.f/3.f, 0.75f, 0.8f, 5.f/6.f,  6.f/7.f,  0.875f};

    float s[8] = {0.f, 0.f, 0.f, 0.f, 0.f, 0.f, 0.f, 0.f};  // w = 1..8

    // ---- phase 1: each 32-lane group row-sums one row of x ----
    const float4* xrow = reinterpret_cast<const float4*>(x + (size_t)(b0 + g) * I_DIM);
    #pragma unroll
    for (int it = 0; it < I_DIM / (32 * 4); ++it) {
        float4 xv = xrow[it * 32 + lg];
        float vals[4] = {xv.x, xv.y, xv.z, xv.w};
        #pragma unroll
        for (int e = 0; e < 4; ++e) {
            float z2 = vals[e] * K;
            float ex = __builtin_amdgcn_exp2f(z2);                    // e^{2z}
            float xs = 1.f - 2.f * __builtin_amdgcn_rcpf(ex + 1.f);   // tanh
            float pm2 = 1.f, pm1 = xs;
            s[0] += xs;
            #pragma unroll
            for (int n = 0; n < 7; ++n) {
                float pn = An[n] * xs * pm1 - Bn[n] * pm2;  // |pn| <= 1, clip is no-op
                s[n + 1] += pn;
                pm2 = pm1; pm1 = pn;
            }
        }
    }

    // reduce within the 32-lane group (masks <=16 stay inside the group)
    #pragma unroll
    for (int w = 0; w < 8; ++w) {
        float v = s[w];
        #pragma unroll
        for (int m = 16; m >= 1; m >>= 1)
            v += __shfl_xor(v, m, 64);
        if (lg == 0) S_lds[g][w] = v;
    }
    __syncthreads();

    // hoist S into registers (8 rows x 8 w)
    float sr[G][8];
    #pragma unroll
    for (int r = 0; r < G; ++r)
        #pragma unroll
        for (int w = 0; w < 8; ++w)
            sr[r][w] = S_lds[r][w];

    // ---- phase 2: out[b0+r][o] for o = t + 256*j ----
    #pragma unroll
    for (int j = 0; j < O_DIM / NT; ++j) {
        const int o = t + NT * j;
        const float* c = coeffs + o * 9;
        const float c0 = c[0], c1 = c[1], c2 = c[2], c3 = c[3], c4 = c[4],
                    c5 = c[5], c6 = c[6], c7 = c[7], c8 = c[8];
        #pragma unroll
        for (int r = 0; r < G; ++r) {
            float acc = c0 * (float)I_DIM;          // w=0 term: sum of ones
            acc = fmaf(c1, sr[r][0], acc);
            acc = fmaf(c2, sr[r][1], acc);
            acc = fmaf(c3, sr[r][2], acc);
            acc = fmaf(c4, sr[r][3], acc);
            acc = fmaf(c5, sr[r][4], acc);
            acc = fmaf(c6, sr[r][5], acc);
            acc = fmaf(c7, sr[r][6], acc);
            acc = fmaf(c8, sr[r][7], acc);
            out[(size_t)(b0 + r) * O_DIM + o] = acc;
        }
    }
}

extern "C" void kernel_launch(void* const* d_in, const int* in_sizes, int n_in,
                              void* d_out, int out_size, void* d_ws, size_t ws_size,
                              hipStream_t stream) {
    const float* x      = (const float*)d_in[0];
    const float* coeffs = (const float*)d_in[1];
    const float* scale  = (const float*)d_in[2];
    float* out          = (float*)d_out;

    const int B = in_sizes[0] / I_DIM;   // 4096
    const int nblocks = B / G;           // 512

    legendre_fused<<<nblocks, NT, 0, stream>>>(x, coeffs, scale, out);
}

// Round 2
// 15.313 us; speedup vs baseline: 1.0290x; 1.0290x over previous
//
#include <hip/hip_runtime.h>

// LegendreActivation: out[b,o] = sum_w coeffs[o,w] * S[b,w]
// where S[b,w] = sum_i P_w(tanh(x[b,i]*scale)),  S[b,0] == 1024 exactly.
// B=4096, I=1024, O=1024, W=9 (degrees 0..8).
//
// R2: occupancy fix. R1 had 512 blocks -> 2 waves/SIMD (latency-bound,
// 2.1 TB/s effective). Now: G=2 rows/block, 2048 blocks, launch_bounds(256,8)
// -> 8 blocks/CU = 32 waves/CU = 8 waves/SIMD. Each wave = half a row
// (2 independent float4 loads/lane).

constexpr int I_DIM = 1024;
constexpr int O_DIM = 1024;
constexpr int NT    = 256;  // 4 waves
constexpr int G     = 2;    // rows per block

__global__ __launch_bounds__(NT, 8) void legendre_fused(
    const float* __restrict__ x,
    const float* __restrict__ coeffs,
    const float* __restrict__ scale_p,
    float* __restrict__ out)
{
    __shared__ float S_part[4][8];  // per-wave partial sums, w = 1..8

    const int t    = threadIdx.x;
    const int wave = t >> 6;        // 0..3
    const int lane = t & 63;
    const int b0   = blockIdx.x * G;
    const int row  = b0 + (wave >> 1);   // waves 0,1 -> row b0; 2,3 -> b0+1
    const int half = wave & 1;           // which 512-float half of the row

    float sc = scale_p[0];
    sc = fminf(fmaxf(sc, 0.1f), 2.0f);
    const float K = sc * 2.8853900817779268f;  // sc * 2*log2(e)

    // ---- phase 1: this wave sums half a row (512 floats = 64 lanes x 8) ----
    const float4* xr =
        reinterpret_cast<const float4*>(x + (size_t)row * I_DIM) + half * 128 + lane;
    const float4 xv0 = xr[0];     // two independent loads, issued back-to-back
    const float4 xv1 = xr[64];

    const float An[7] = {1.5f, 5.f/3.f, 1.75f, 1.8f, 11.f/6.f, 13.f/7.f, 1.875f};
    const float Bn[7] = {0.5f, 2.f/3.f, 0.75f, 0.8f, 5.f/6.f,  6.f/7.f,  0.875f};

    float s[8] = {0.f, 0.f, 0.f, 0.f, 0.f, 0.f, 0.f, 0.f};  // w = 1..8
    const float vals[8] = {xv0.x, xv0.y, xv0.z, xv0.w, xv1.x, xv1.y, xv1.z, xv1.w};
    #pragma unroll
    for (int e = 0; e < 8; ++e) {
        float ex = __builtin_amdgcn_exp2f(vals[e] * K);                // e^{2z}
        float xs = 1.f - 2.f * __builtin_amdgcn_rcpf(ex + 1.f);       // tanh
        float pm2 = 1.f, pm1 = xs;
        s[0] += xs;
        #pragma unroll
        for (int n = 0; n < 7; ++n) {
            float pn = An[n] * xs * pm1 - Bn[n] * pm2;  // |pn|<=1, clip is no-op
            s[n + 1] += pn;
            pm2 = pm1; pm1 = pn;
        }
    }

    // full 64-lane butterfly reduce for each of the 8 sums
    #pragma unroll
    for (int w = 0; w < 8; ++w) {
        float v = s[w];
        #pragma unroll
        for (int m = 32; m >= 1; m >>= 1)
            v += __shfl_xor(v, m, 64);
        if (lane == 0) S_part[wave][w] = v;
    }
    __syncthreads();

    // combine the two half-row partials per row
    float sr0[8], sr1[8];
    #pragma unroll
    for (int w = 0; w < 8; ++w) {
        sr0[w] = S_part[0][w] + S_part[1][w];
        sr1[w] = S_part[2][w] + S_part[3][w];
    }

    // ---- phase 2: out[b0..b0+1][o] for o = t + 256*j ----
    #pragma unroll
    for (int j = 0; j < O_DIM / NT; ++j) {
        const int o = t + NT * j;
        const float* c = coeffs + o * 9;
        const float c0 = c[0], c1 = c[1], c2 = c[2], c3 = c[3], c4 = c[4],
                    c5 = c[5], c6 = c[6], c7 = c[7], c8 = c[8];

        float a0 = c0 * (float)I_DIM;   // w=0 term: sum of ones
        a0 = fmaf(c1, sr0[0], a0); a0 = fmaf(c2, sr0[1], a0);
        a0 = fmaf(c3, sr0[2], a0); a0 = fmaf(c4, sr0[3], a0);
        a0 = fmaf(c5, sr0[4], a0); a0 = fmaf(c6, sr0[5], a0);
        a0 = fmaf(c7, sr0[6], a0); a0 = fmaf(c8, sr0[7], a0);

        float a1 = c0 * (float)I_DIM;
        a1 = fmaf(c1, sr1[0], a1); a1 = fmaf(c2, sr1[1], a1);
        a1 = fmaf(c3, sr1[2], a1); a1 = fmaf(c4, sr1[3], a1);
        a1 = fmaf(c5, sr1[4], a1); a1 = fmaf(c6, sr1[5], a1);
        a1 = fmaf(c7, sr1[6], a1); a1 = fmaf(c8, sr1[7], a1);

        out[(size_t)b0 * O_DIM + o]       = a0;
        out[(size_t)(b0 + 1) * O_DIM + o] = a1;
    }
}

extern "C" void kernel_launch(void* const* d_in, const int* in_sizes, int n_in,
                              void* d_out, int out_size, void* d_ws, size_t ws_size,
                              hipStream_t stream) {
    const float* x      = (const float*)d_in[0];
    const float* coeffs = (const float*)d_in[1];
    const float* scale  = (const float*)d_in[2];
    float* out          = (float*)d_out;

    const int B = in_sizes[0] / I_DIM;   // 4096
    const int nblocks = B / G;           // 2048

    legendre_fused<<<nblocks, NT, 0, stream>>>(x, coeffs, scale, out);
}

// Round 3
// 14.495 us; speedup vs baseline: 1.0871x; 1.0564x over previous
//
#include <hip/hip_runtime.h>

// LegendreActivation: out[b,o] = sum_w coeffs[o,w] * S[b,w]
// where S[b,w] = sum_i P_w(tanh(x[b,i]*scale)),  S[b,0] == 1024 exactly.
// B=4096, I=1024, O=1024, W=9 (degrees 0..8).
//
// R3: kill the coeff gather. R1/R2 were bound by phase-2 coefficient loads
// (36 scalar gathers/thread, 1152 instr/CU x ~30cy of L1 line-touches).
// Now: thread t owns o=4t..4t+3 -> its 36 coeffs are 144 CONTIGUOUS bytes
// = 9 float4 loads, loaded once per block and reused for G=4 rows.
// One wave per row (16 elem/lane), float4 stores.

constexpr int I_DIM = 1024;
constexpr int O_DIM = 1024;
constexpr int NT    = 256;   // 4 waves
constexpr int G     = 4;     // rows per block, one wave per row

__global__ __launch_bounds__(NT, 4) void legendre_fused(
    const float* __restrict__ x,
    const float* __restrict__ coeffs,
    const float* __restrict__ scale_p,
    float* __restrict__ out)
{
    __shared__ float S_lds[G][8];   // per-row sums, w = 1..8

    const int t    = threadIdx.x;
    const int wave = t >> 6;        // 0..3 -> owns row b0+wave
    const int lane = t & 63;
    const int b0   = blockIdx.x * G;
    const int row  = b0 + wave;

    float sc = fminf(fmaxf(scale_p[0], 0.1f), 2.0f);
    const float K = sc * 2.8853900817779268f;  // sc * 2*log2(e)

    // ---- coeff load: 144 contiguous bytes per thread (o = 4t..4t+3) ----
    // issued first so the L1/L2 traffic overlaps the x loads below.
    float c[36];   // c[ol*9 + w] = coeffs[(4t+ol)*9 + w]
    {
        const float4* ct4 = reinterpret_cast<const float4*>(coeffs) + (size_t)t * 9;
        #pragma unroll
        for (int k = 0; k < 9; ++k) {
            float4 v = ct4[k];
            c[4 * k + 0] = v.x; c[4 * k + 1] = v.y;
            c[4 * k + 2] = v.z; c[4 * k + 3] = v.w;
        }
    }

    // ---- phase 1: this wave sums one full row (1024 = 64 lanes x 16) ----
    const float4* xr = reinterpret_cast<const float4*>(x + (size_t)row * I_DIM) + lane;
    float4 xv[4];
    #pragma unroll
    for (int k = 0; k < 4; ++k) xv[k] = xr[k * 64];   // 4 independent 16B loads

    const float An[7] = {1.5f, 5.f/3.f, 1.75f, 1.8f, 11.f/6.f, 13.f/7.f, 1.875f};
    const float Bn[7] = {0.5f, 2.f/3.f, 0.75f, 0.8f, 5.f/6.f,  6.f/7.f,  0.875f};

    float s[8] = {0.f, 0.f, 0.f, 0.f, 0.f, 0.f, 0.f, 0.f};  // w = 1..8
    #pragma unroll
    for (int k = 0; k < 4; ++k) {
        const float vals[4] = {xv[k].x, xv[k].y, xv[k].z, xv[k].w};
        #pragma unroll
        for (int e = 0; e < 4; ++e) {
            float ex = __builtin_amdgcn_exp2f(vals[e] * K);              // e^{2z}
            float xs = 1.f - 2.f * __builtin_amdgcn_rcpf(ex + 1.f);      // tanh
            float pm2 = 1.f, pm1 = xs;
            s[0] += xs;
            #pragma unroll
            for (int n = 0; n < 7; ++n) {
                float pn = An[n] * xs * pm1 - Bn[n] * pm2;  // |pn|<=1, clip no-op
                s[n + 1] += pn;
                pm2 = pm1; pm1 = pn;
            }
        }
    }

    // 64-lane butterfly; one reduction per row (was two in R2)
    #pragma unroll
    for (int w = 0; w < 8; ++w) {
        float v = s[w];
        #pragma unroll
        for (int m = 32; m >= 1; m >>= 1)
            v += __shfl_xor(v, m, 64);
        if (lane == 0) S_lds[wave][w] = v;
    }
    __syncthreads();

    // ---- phase 2: each thread writes out[b0+r][4t..4t+3] for r = 0..3 ----
    #pragma unroll
    for (int r = 0; r < G; ++r) {
        // wave-uniform broadcast reads of the row sums
        float s0 = S_lds[r][0], s1 = S_lds[r][1], s2 = S_lds[r][2], s3 = S_lds[r][3];
        float s4 = S_lds[r][4], s5 = S_lds[r][5], s6 = S_lds[r][6], s7 = S_lds[r][7];

        float4 acc;
        float* ap = &acc.x;
        #pragma unroll
        for (int ol = 0; ol < 4; ++ol) {
            float a = c[ol * 9 + 0] * (float)I_DIM;   // w=0: sum of ones
            a = fmaf(c[ol * 9 + 1], s0, a);
            a = fmaf(c[ol * 9 + 2], s1, a);
            a = fmaf(c[ol * 9 + 3], s2, a);
            a = fmaf(c[ol * 9 + 4], s3, a);
            a = fmaf(c[ol * 9 + 5], s4, a);
            a = fmaf(c[ol * 9 + 6], s5, a);
            a = fmaf(c[ol * 9 + 7], s6, a);
            a = fmaf(c[ol * 9 + 8], s7, a);
            ap[ol] = a;
        }
        *reinterpret_cast<float4*>(out + (size_t)(b0 + r) * O_DIM + 4 * t) = acc;
    }
}

extern "C" void kernel_launch(void* const* d_in, const int* in_sizes, int n_in,
                              void* d_out, int out_size, void* d_ws, size_t ws_size,
                              hipStream_t stream) {
    const float* x      = (const float*)d_in[0];
    const float* coeffs = (const float*)d_in[1];
    const float* scale  = (const float*)d_in[2];
    float* out          = (float*)d_out;

    const int B = in_sizes[0] / I_DIM;   // 4096
    const int nblocks = B / G;           // 1024

    legendre_fused<<<nblocks, NT, 0, stream>>>(x, coeffs, scale, out);
}

// Round 4
// 12.859 us; speedup vs baseline: 1.2254x; 1.1273x over previous
//
#include <hip/hip_runtime.h>

// LegendreActivation: out[b,o] = sum_w coeffs[o,w] * S[b,w]
// where S[b,w] = sum_i P_w(tanh(x[b,i]*scale)),  S[b,0] == 1024 exactly.
//
// R4: power-sum reformulation. Per element compute only the power sums
// M_k = sum_i xs^k (7 mul + 8 add + tanh ~= 20 VALU/elem vs ~35 for the
// Bonnet recursion). After the 64-lane butterfly every lane holds the full
// row sums M_1..M_8; convert to Legendre sums S_w once per row via the
// constant monomial-basis matrix (~20 fma, negligible). Phase 2 unchanged.
// Discriminates kernel-bound (dur drops ~1-1.5us) vs dispatch-overhead floor.

constexpr int I_DIM = 1024;
constexpr int O_DIM = 1024;
constexpr int NT    = 256;   // 4 waves
constexpr int G     = 4;     // rows per block, one wave per row

__global__ __launch_bounds__(NT, 4) void legendre_fused(
    const float* __restrict__ x,
    const float* __restrict__ coeffs,
    const float* __restrict__ scale_p,
    float* __restrict__ out)
{
    __shared__ float S_lds[G][8];   // per-row Legendre sums, w = 1..8

    const int t    = threadIdx.x;
    const int wave = t >> 6;        // 0..3 -> owns row b0+wave
    const int lane = t & 63;
    const int b0   = blockIdx.x * G;
    const int row  = b0 + wave;

    float sc = fminf(fmaxf(scale_p[0], 0.1f), 2.0f);
    const float K = sc * 2.8853900817779268f;  // sc * 2*log2(e)

    // ---- coeff load: 144 contiguous bytes per thread (o = 4t..4t+3) ----
    float c[36];   // c[ol*9 + w] = coeffs[(4t+ol)*9 + w]
    {
        const float4* ct4 = reinterpret_cast<const float4*>(coeffs) + (size_t)t * 9;
        #pragma unroll
        for (int k = 0; k < 9; ++k) {
            float4 v = ct4[k];
            c[4 * k + 0] = v.x; c[4 * k + 1] = v.y;
            c[4 * k + 2] = v.z; c[4 * k + 3] = v.w;
        }
    }

    // ---- phase 1: power sums over one full row (1024 = 64 lanes x 16) ----
    const float4* xr = reinterpret_cast<const float4*>(x + (size_t)row * I_DIM) + lane;
    float4 xv[4];
    #pragma unroll
    for (int k = 0; k < 4; ++k) xv[k] = xr[k * 64];   // 4 independent 16B loads

    float m[8] = {0.f, 0.f, 0.f, 0.f, 0.f, 0.f, 0.f, 0.f};  // M_1..M_8 partials
    #pragma unroll
    for (int k = 0; k < 4; ++k) {
        const float vals[4] = {xv[k].x, xv[k].y, xv[k].z, xv[k].w};
        #pragma unroll
        for (int e = 0; e < 4; ++e) {
            float ex = __builtin_amdgcn_exp2f(vals[e] * K);           // e^{2z}
            float xs = fmaf(-2.f, __builtin_amdgcn_rcpf(ex + 1.f), 1.f);  // tanh
            float p2 = xs * xs;
            float p3 = p2 * xs;
            float p4 = p2 * p2;
            float p5 = p3 * p2;
            float p6 = p3 * p3;
            float p7 = p4 * p3;
            float p8 = p4 * p4;
            m[0] += xs; m[1] += p2; m[2] += p3; m[3] += p4;
            m[4] += p5; m[5] += p6; m[6] += p7; m[7] += p8;
        }
    }

    // 64-lane butterfly: afterwards EVERY lane holds the full row sums
    #pragma unroll
    for (int w = 0; w < 8; ++w) {
        #pragma unroll
        for (int msk = 32; msk >= 1; msk >>= 1)
            m[w] += __shfl_xor(m[w], msk, 64);
    }

    // monomial power sums -> Legendre sums (per row, every lane redundant)
    {
        const float M1 = m[0], M2 = m[1], M3 = m[2], M4 = m[3],
                    M5 = m[4], M6 = m[5], M7 = m[6], M8 = m[7];
        const float N = (float)I_DIM;   // M_0
        float S1 = M1;
        float S2 = 1.5f * M2 - 0.5f * N;
        float S3 = 2.5f * M3 - 1.5f * M1;
        float S4 = 4.375f * M4 - 3.75f * M2 + 0.375f * N;
        float S5 = 7.875f * M5 - 8.75f * M3 + 1.875f * M1;
        float S6 = 14.4375f * M6 - 19.6875f * M4 + 6.5625f * M2 - 0.3125f * N;
        float S7 = 26.8125f * M7 - 43.3125f * M5 + 19.6875f * M3 - 2.1875f * M1;
        float S8 = 50.2734375f * M8 - 93.84375f * M6 + 54.140625f * M4
                 - 9.84375f * M2 + 0.2734375f * N;
        if (lane == 0) {
            S_lds[wave][0] = S1; S_lds[wave][1] = S2;
            S_lds[wave][2] = S3; S_lds[wave][3] = S4;
            S_lds[wave][4] = S5; S_lds[wave][5] = S6;
            S_lds[wave][6] = S7; S_lds[wave][7] = S8;
        }
    }
    __syncthreads();

    // ---- phase 2: each thread writes out[b0+r][4t..4t+3] for r = 0..3 ----
    #pragma unroll
    for (int r = 0; r < G; ++r) {
        float s0 = S_lds[r][0], s1 = S_lds[r][1], s2 = S_lds[r][2], s3 = S_lds[r][3];
        float s4 = S_lds[r][4], s5 = S_lds[r][5], s6 = S_lds[r][6], s7 = S_lds[r][7];

        float4 acc;
        float* ap = &acc.x;
        #pragma unroll
        for (int ol = 0; ol < 4; ++ol) {
            float a = c[ol * 9 + 0] * (float)I_DIM;   // w=0: sum of ones
            a = fmaf(c[ol * 9 + 1], s0, a);
            a = fmaf(c[ol * 9 + 2], s1, a);
            a = fmaf(c[ol * 9 + 3], s2, a);
            a = fmaf(c[ol * 9 + 4], s3, a);
            a = fmaf(c[ol * 9 + 5], s4, a);
            a = fmaf(c[ol * 9 + 6], s5, a);
            a = fmaf(c[ol * 9 + 7], s6, a);
            a = fmaf(c[ol * 9 + 8], s7, a);
            ap[ol] = a;
        }
        *reinterpret_cast<float4*>(out + (size_t)(b0 + r) * O_DIM + 4 * t) = acc;
    }
}

extern "C" void kernel_launch(void* const* d_in, const int* in_sizes, int n_in,
                              void* d_out, int out_size, void* d_ws, size_t ws_size,
                              hipStream_t stream) {
    const float* x      = (const float*)d_in[0];
    const float* coeffs = (const float*)d_in[1];
    const float* scale  = (const float*)d_in[2];
    float* out          = (float*)d_out;

    const int B = in_sizes[0] / I_DIM;   // 4096
    const int nblocks = B / G;           // 1024

    legendre_fused<<<nblocks, NT, 0, stream>>>(x, coeffs, scale, out);
}

// Round 6
// 11.779 us; speedup vs baseline: 1.3378x; 1.0917x over previous
//
#include <hip/hip_runtime.h>

// LegendreActivation: out[b,o] = sum_w coeffs[o,w] * S[b,w]
// where S[b,w] = sum_i P_w(tanh(x[b,i]*scale)),  S[b,0] == 1024 exactly.
//
// R6 = R5 with the compile fix: __builtin_nontemporal_store needs a native
// clang vector type (ext_vector_type), not HIP's float4 class.
// (a) fmac fusion in power sums (11 ops/elem), (b) nontemporal float4-wide
// stores for `out` (streaming, keep x in L2), (c) loads issued up front.

constexpr int I_DIM = 1024;
constexpr int O_DIM = 1024;
constexpr int NT    = 256;   // 4 waves
constexpr int G     = 4;     // rows per block, one wave per row

typedef float f32x4 __attribute__((ext_vector_type(4)));

__global__ __launch_bounds__(NT, 4) void legendre_fused(
    const float* __restrict__ x,
    const float* __restrict__ coeffs,
    const float* __restrict__ scale_p,
    float* __restrict__ out)
{
    __shared__ float S_lds[G][8];   // per-row Legendre sums, w = 1..8

    const int t    = threadIdx.x;
    const int wave = t >> 6;        // 0..3 -> owns row b0+wave
    const int lane = t & 63;
    const int b0   = blockIdx.x * G;
    const int row  = b0 + wave;

    // ---- issue all global loads up front ----
    const float4* xr = reinterpret_cast<const float4*>(x + (size_t)row * I_DIM) + lane;
    float4 xv0 = xr[0];
    float4 xv1 = xr[64];
    float4 xv2 = xr[128];
    float4 xv3 = xr[192];

    const float4* ct4 = reinterpret_cast<const float4*>(coeffs) + (size_t)t * 9;
    float4 cv[9];
    #pragma unroll
    for (int k = 0; k < 9; ++k) cv[k] = ct4[k];

    float sc = fminf(fmaxf(scale_p[0], 0.1f), 2.0f);
    const float K = sc * 2.8853900817779268f;  // sc * 2*log2(e)

    // ---- phase 1: power sums M_1..M_8 over one row (64 lanes x 16) ----
    float m1 = 0.f, m2 = 0.f, m3 = 0.f, m4 = 0.f,
          m5 = 0.f, m6 = 0.f, m7 = 0.f, m8 = 0.f;

    const float vals[16] = {xv0.x, xv0.y, xv0.z, xv0.w,
                            xv1.x, xv1.y, xv1.z, xv1.w,
                            xv2.x, xv2.y, xv2.z, xv2.w,
                            xv3.x, xv3.y, xv3.z, xv3.w};
    #pragma unroll
    for (int e = 0; e < 16; ++e) {
        float ex = __builtin_amdgcn_exp2f(vals[e] * K);               // e^{2z}
        float xs = fmaf(-2.f, __builtin_amdgcn_rcpf(ex + 1.f), 1.f);  // tanh
        float p2 = xs * xs;           // mul
        float p3 = p2 * xs;           // mul
        float p4 = p2 * p2;           // mul
        m1 += xs;                     // add
        m2 += p2;                     // add
        m3 += p3;                     // add
        m4 += p4;                     // add
        m5 = fmaf(p2, p3, m5);        // fmac
        m6 = fmaf(p3, p3, m6);        // fmac
        m7 = fmaf(p3, p4, m7);        // fmac
        m8 = fmaf(p4, p4, m8);        // fmac
    }

    // 64-lane butterfly: afterwards every lane holds the full row sums
    float mm[8] = {m1, m2, m3, m4, m5, m6, m7, m8};
    #pragma unroll
    for (int w = 0; w < 8; ++w) {
        #pragma unroll
        for (int msk = 32; msk >= 1; msk >>= 1)
            mm[w] += __shfl_xor(mm[w], msk, 64);
    }

    // monomial power sums -> Legendre sums (lane 0 writes)
    if (lane == 0) {
        const float M1 = mm[0], M2 = mm[1], M3 = mm[2], M4 = mm[3],
                    M5 = mm[4], M6 = mm[5], M7 = mm[6], M8 = mm[7];
        const float N = (float)I_DIM;   // M_0
        S_lds[wave][0] = M1;
        S_lds[wave][1] = 1.5f * M2 - 0.5f * N;
        S_lds[wave][2] = 2.5f * M3 - 1.5f * M1;
        S_lds[wave][3] = 4.375f * M4 - 3.75f * M2 + 0.375f * N;
        S_lds[wave][4] = 7.875f * M5 - 8.75f * M3 + 1.875f * M1;
        S_lds[wave][5] = 14.4375f * M6 - 19.6875f * M4 + 6.5625f * M2 - 0.3125f * N;
        S_lds[wave][6] = 26.8125f * M7 - 43.3125f * M5 + 19.6875f * M3 - 2.1875f * M1;
        S_lds[wave][7] = 50.2734375f * M8 - 93.84375f * M6 + 54.140625f * M4
                       - 9.84375f * M2 + 0.2734375f * N;
    }
    __syncthreads();

    // ---- phase 2: each thread writes out[b0+r][4t..4t+3] for r = 0..3 ----
    // unpack coeffs: c[ol*9 + w]
    float c[36];
    #pragma unroll
    for (int k = 0; k < 9; ++k) {
        c[4 * k + 0] = cv[k].x; c[4 * k + 1] = cv[k].y;
        c[4 * k + 2] = cv[k].z; c[4 * k + 3] = cv[k].w;
    }

    #pragma unroll
    for (int r = 0; r < G; ++r) {
        float s0 = S_lds[r][0], s1 = S_lds[r][1], s2 = S_lds[r][2], s3 = S_lds[r][3];
        float s4 = S_lds[r][4], s5 = S_lds[r][5], s6 = S_lds[r][6], s7 = S_lds[r][7];

        f32x4 acc;
        #pragma unroll
        for (int ol = 0; ol < 4; ++ol) {
            float a = c[ol * 9 + 0] * (float)I_DIM;   // w=0: sum of ones
            a = fmaf(c[ol * 9 + 1], s0, a);
            a = fmaf(c[ol * 9 + 2], s1, a);
            a = fmaf(c[ol * 9 + 3], s2, a);
            a = fmaf(c[ol * 9 + 4], s3, a);
            a = fmaf(c[ol * 9 + 5], s4, a);
            a = fmaf(c[ol * 9 + 6], s5, a);
            a = fmaf(c[ol * 9 + 7], s6, a);
            a = fmaf(c[ol * 9 + 8], s7, a);
            acc[ol] = a;
        }
        // streaming store: don't pollute L2 (keeps x resident across replays)
        __builtin_nontemporal_store(acc,
            reinterpret_cast<f32x4*>(out + (size_t)(b0 + r) * O_DIM + 4 * t));
    }
}

extern "C" void kernel_launch(void* const* d_in, const int* in_sizes, int n_in,
                              void* d_out, int out_size, void* d_ws, size_t ws_size,
                              hipStream_t stream) {
    const float* x      = (const float*)d_in[0];
    const float* coeffs = (const float*)d_in[1];
    const float* scale  = (const float*)d_in[2];
    float* out          = (float*)d_out;

    const int B = in_sizes[0] / I_DIM;   // 4096
    const int nblocks = B / G;           // 1024

    legendre_fused<<<nblocks, NT, 0, stream>>>(x, coeffs, scale, out);
}